// Round 7
// baseline (651.467 us; speedup 1.0000x reference)
//
#include <hip/hip_runtime.h>

#define NPTS 2000
#define NBATCH 8
#define NC 256
#define NW 128
#define NK 10
#define NROWS (NBATCH * NPTS)
#define JPAD 2048
#define PL2 (JPAD * 32)            // f16 elems per (b,kc,hl) plane

typedef _Float16 f16x8 __attribute__((ext_vector_type(8)));
typedef _Float16 f16x4 __attribute__((ext_vector_type(4)));
typedef float f32x4 __attribute__((ext_vector_type(4)));

__device__ __forceinline__ float dot4(float4 a, float4 b) {
    return a.x*b.x + a.y*b.y + a.z*b.z + a.w*b.w;
}
__device__ __forceinline__ float4 relu4(float4 a) {
    return make_float4(fmaxf(a.x,0.f), fmaxf(a.y,0.f), fmaxf(a.z,0.f), fmaxf(a.w,0.f));
}
__device__ __forceinline__ float4 add4(float4 a, float4 b) {
    return make_float4(a.x+b.x, a.y+b.y, a.z+b.z, a.w+b.w);
}

__device__ __forceinline__ void ins10(float d, int j, float* vals, int* idxs) {
    if (d > vals[9]) {
        float v = d; int id = j;
        #pragma unroll
        for (int s = 0; s < 10; ++s) {
            if (v > vals[s]) {
                float tv = vals[s]; vals[s] = v; v = tv;
                int   ti = idxs[s]; idxs[s] = id; id = ti;
            }
        }
    }
}

// ---------------- Kernel P: transpose to planar f16 hi/lo + row norms ----------------
// xb: [b][kc(8)][hl(2)][2048 j][32 c] f16. Rows >= NPTS zero-filled.
__global__ __launch_bounds__(256) void k_prep(
    const float* __restrict__ x, _Float16* __restrict__ xb,
    float* __restrict__ xx)
{
    __shared__ float T[64][259];
    __shared__ float Pp[64][4];
    const int t  = threadIdx.x;
    const int b  = blockIdx.x >> 5;
    const int n0 = (blockIdx.x & 31) * 64;

    #pragma unroll
    for (int p = 0; p < 64; ++p) {
        const int idx = p*256 + t;
        const int c = idx >> 6, nl = idx & 63;
        T[nl][c] = x[((size_t)b*NC + c)*NPTS + min(n0 + nl, NPTS-1)];
    }
    __syncthreads();

    const int row = t & 63, q = t >> 6;   // q -> kc planes 2q, 2q+1
    const int gr  = n0 + row;
    const bool ok = gr < NPTS;
    float ss = 0.f;
    #pragma unroll
    for (int u = 0; u < 2; ++u) {
        const int kc = 2*q + u;
        const size_t bh = ((size_t)(b*8 + kc)*2    )*PL2 + (size_t)gr*32;
        const size_t bl = ((size_t)(b*8 + kc)*2 + 1)*PL2 + (size_t)gr*32;
        #pragma unroll
        for (int g = 0; g < 4; ++g) {
            f16x8 vh, vl;
            #pragma unroll
            for (int e = 0; e < 8; ++e) {
                const float f = ok ? T[row][kc*32 + g*8 + e] : 0.f;
                ss = fmaf(f, f, ss);
                const _Float16 h = (_Float16)f;
                vh[e] = h;
                vl[e] = (_Float16)(f - (float)h);
            }
            *(f16x8*)&xb[bh + g*8] = vh;
            *(f16x8*)&xb[bl + g*8] = vl;
        }
    }
    Pp[row][q] = ss;
    __syncthreads();
    if (t < 64 && n0 + t < NPTS)
        xx[(size_t)b*NPTS + n0 + t] = Pp[t][0] + Pp[t][1] + Pp[t][2] + Pp[t][3];
}

// ---------------- Kernel W: f32 -> f16 weight conversion ----------------
__global__ __launch_bounds__(256) void k_wprep(const float* __restrict__ a,
                                               _Float16* __restrict__ o, int n)
{
    const int i = (blockIdx.x*256 + threadIdx.x)*4;
    if (i < n) {
        const float4 v = *(const float4*)&a[i];
        f16x4 h = {(_Float16)v.x, (_Float16)v.y, (_Float16)v.z, (_Float16)v.w};
        *(f16x4*)&o[i] = h;
    }
}

// ---------------- Kernel A: row GEMM -> T1r / P / Q (unchanged) ----------------
__global__ __launch_bounds__(256) void k_rowgemm(
    const float* __restrict__ x,
    const float* __restrict__ tW1, const float* __restrict__ tb1,
    const float* __restrict__ sW1, const float* __restrict__ sb1,
    float* __restrict__ T1r, float* __restrict__ P, float* __restrict__ Q)
{
    __shared__ float Xs[32][34];
    __shared__ float Ws[32][132];
    const int t  = threadIdx.x;
    const int r0 = blockIdx.x * 32;
    const int sel = blockIdx.y;
    const int jq = t & 15,  iq = t >> 4;
    const int j0 = jq * 8,  i0 = iq * 2;

    float acc[2][8];
    #pragma unroll
    for (int a = 0; a < 2; ++a)
        #pragma unroll
        for (int q = 0; q < 8; ++q) acc[a][q] = 0.f;

    const int li = t & 31;
    const int lk = t >> 5;
    const int rl = r0 + li;
    const int lb = rl / NPTS, ln = rl % NPTS;

    for (int c0 = 0; c0 < NC; c0 += 32) {
        #pragma unroll
        for (int p = 0; p < 4; ++p) {
            int kk = lk + p * 8;
            Xs[kk][li] = x[((size_t)lb * NC + c0 + kk) * NPTS + ln];
        }
        #pragma unroll
        for (int jj = 0; jj < 16; ++jj) {
            int j = jj * 8 + lk;
            int c = c0 + li;
            float w;
            if (sel == 0)      w = tW1[j * NC + c];
            else if (sel == 1) w = sW1[j * (2*NC) + c];
            else               w = sW1[j * (2*NC) + NC + c];
            Ws[li][j] = w;
        }
        __syncthreads();
        #pragma unroll 8
        for (int kk = 0; kk < 32; ++kk) {
            const float2 xv = *(const float2*)&Xs[kk][i0];
            const float4 w0 = *(const float4*)&Ws[kk][j0];
            const float4 w1 = *(const float4*)&Ws[kk][j0 + 4];
            float w[8] = {w0.x,w0.y,w0.z,w0.w,w1.x,w1.y,w1.z,w1.w};
            #pragma unroll
            for (int q = 0; q < 8; ++q) {
                acc[0][q] = fmaf(xv.x, w[q], acc[0][q]);
                acc[1][q] = fmaf(xv.y, w[q], acc[1][q]);
            }
        }
        __syncthreads();
    }

    #pragma unroll
    for (int a = 0; a < 2; ++a) {
        const int r = r0 + i0 + a;
        float o[8];
        #pragma unroll
        for (int q = 0; q < 8; ++q) {
            float v = acc[a][q];
            if (sel == 0)      { v += tb1[j0+q]; v = fmaxf(v, 0.f); }
            else if (sel == 2) { v += sb1[j0+q]; }
            o[q] = v;
        }
        float* dst = (sel==0 ? T1r : (sel==1 ? P : Q)) + (size_t)r * NW + j0;
        *(float4*)dst       = make_float4(o[0],o[1],o[2],o[3]);
        *(float4*)(dst + 4) = make_float4(o[4],o[5],o[6],o[7]);
    }
}

// ---------------- Kernel B v5: barrier-free streaming MFMA distance + reg top-10 ----------------
// 1-wave block: 32 i-rows resident in regs (B operand), j streamed global->reg (A operand).
// Grid 1024 = 8 batches x 64 i-groups x 2 j-halves; partial top-10 lists to pval/pidx.
__global__ __launch_bounds__(64, 1) void k_topk(
    const _Float16* __restrict__ xb, const float* __restrict__ xx,
    float* __restrict__ pval, int* __restrict__ pidx)
{
    __shared__ float mval[128*10];
    __shared__ int   midx[128*10];

    const int t  = threadIdx.x;
    const int b  = blockIdx.x & 7;            // batch -> XCD
    const int ig = (blockIdx.x >> 3) & 63;
    const int jh = blockIdx.x >> 9;           // j-half
    const int i0 = ig * 32;
    const int lr = t & 15, rg = t >> 4;
    const size_t bb = (size_t)b * 16 * PL2;
    const size_t fo = (size_t)lr * 32 + rg * 8;   // lane offset within a plane row-block

    // resident B-fragments: 2 i-tiles x 8 kc x (hi,lo)
    f16x8 bh[2][8], bl[2][8];
    #pragma unroll
    for (int it = 0; it < 2; ++it)
        #pragma unroll
        for (int kc = 0; kc < 8; ++kc) {
            const size_t ph = bb + (size_t)(kc*2)*PL2 + (size_t)(i0 + it*16)*32 + fo;
            bh[it][kc] = *(const f16x8*)&xb[ph];
            bl[it][kc] = *(const f16x8*)&xb[ph + PL2];
        }

    float v0[10], v1[10]; int x0[10], x1[10];
    #pragma unroll
    for (int s = 0; s < 10; ++s) { v0[s]=v1[s]=-3.0e38f; x0[s]=x1[s]=0x7fffffff; }

    const float* xxp = xx + (size_t)b * NPTS;
    const int jt0 = jh * 63;
    const int jt1 = jh ? 125 : 63;      // 125 tiles cover j 0..1999 exactly

    for (int jt = jt0; jt < jt1; ++jt) {
        const int j0 = jt * 16;
        f32x4 acc0 = {0.f,0.f,0.f,0.f}, acc1 = {0.f,0.f,0.f,0.f};
        #pragma unroll
        for (int h2 = 0; h2 < 2; ++h2) {
            f16x8 ah[4], al[4];
            #pragma unroll
            for (int k4 = 0; k4 < 4; ++k4) {
                const int kc = h2*4 + k4;
                const size_t pa = bb + (size_t)(kc*2)*PL2 + (size_t)j0*32 + fo;
                ah[k4] = *(const f16x8*)&xb[pa];
                al[k4] = *(const f16x8*)&xb[pa + PL2];
            }
            #pragma unroll
            for (int k4 = 0; k4 < 4; ++k4) {
                const int kc = h2*4 + k4;
                acc0 = __builtin_amdgcn_mfma_f32_16x16x32_f16(ah[k4], bh[0][kc], acc0, 0,0,0);
                acc1 = __builtin_amdgcn_mfma_f32_16x16x32_f16(ah[k4], bh[1][kc], acc1, 0,0,0);
                acc0 = __builtin_amdgcn_mfma_f32_16x16x32_f16(ah[k4], bl[0][kc], acc0, 0,0,0);
                acc1 = __builtin_amdgcn_mfma_f32_16x16x32_f16(ah[k4], bl[1][kc], acc1, 0,0,0);
                acc0 = __builtin_amdgcn_mfma_f32_16x16x32_f16(al[k4], bh[0][kc], acc0, 0,0,0);
                acc1 = __builtin_amdgcn_mfma_f32_16x16x32_f16(al[k4], bh[1][kc], acc1, 0,0,0);
            }
        }
        // selection: lane's j's = j0 + rg*4 + q (all < 2000), ascending
        const f32x4 xv = *(const f32x4*)&xxp[j0 + rg*4];
        #pragma unroll
        for (int q = 0; q < 4; ++q) {
            const int j = j0 + rg*4 + q;
            ins10(2.f*acc0[q] - xv[q], j, v0, x0);
            ins10(2.f*acc1[q] - xv[q], j, v1, x1);
        }
    }

    // merge 4 rg-lists per (i-tile, lr) and emit partials
    #pragma unroll
    for (int s = 0; s < 10; ++s) {
        mval[t*10 + s]        = v0[s];  midx[t*10 + s]        = x0[s];
        mval[(64 + t)*10 + s] = v1[s];  midx[(64 + t)*10 + s] = x1[s];
    }
    __syncthreads();
    {   // step1: 64 workers: merge (pr, pr+2) -> pr
        const int it = t >> 5, pr = (t >> 4) & 1, l = t & 15;
        float* va = &mval[(it*64 + pr*16 + l)*10];
        int*   ia = &midx[(it*64 + pr*16 + l)*10];
        const float* vb = &mval[(it*64 + (pr+2)*16 + l)*10];
        const int*   ib = &midx[(it*64 + (pr+2)*16 + l)*10];
        float ov[10]; int oi[10]; int pa = 0, pb = 0;
        #pragma unroll
        for (int s = 0; s < 10; ++s) {
            const float A = va[pa], Bv = vb[pb];
            const int  Ai = ia[pa], Bi = ib[pb];
            const bool ta = (A > Bv) || (A == Bv && Ai < Bi);
            ov[s] = ta ? A : Bv; oi[s] = ta ? Ai : Bi;
            pa += ta ? 1 : 0; pb += ta ? 0 : 1;
        }
        #pragma unroll
        for (int s = 0; s < 10; ++s) { va[s] = ov[s]; ia[s] = oi[s]; }
    }
    __syncthreads();
    if (t < 32) {   // step2: final merge + write partials
        const int it = t >> 4, l = t & 15;
        const float* va = &mval[(it*64 + l)*10];
        const int*   ia = &midx[(it*64 + l)*10];
        const float* vb = &mval[(it*64 + 16 + l)*10];
        const int*   ib = &midx[(it*64 + 16 + l)*10];
        const int i = i0 + it*16 + l;
        if (i < NPTS) {
            float* ov = &pval[((size_t)(b*NPTS + i)*2 + jh)*10];
            int*   oi = &pidx[((size_t)(b*NPTS + i)*2 + jh)*10];
            int pa = 0, pb = 0;
            #pragma unroll
            for (int s = 0; s < 10; ++s) {
                const float A = va[pa], Bv = vb[pb];
                const int  Ai = ia[pa], Bi = ib[pb];
                const bool ta = (A > Bv) || (A == Bv && Ai < Bi);
                ov[s] = ta ? A : Bv; oi[s] = ta ? Ai : Bi;
                pa += ta ? 1 : 0; pb += ta ? 0 : 1;
            }
        }
    }
}

// ---------------- Kernel M: merge the two j-half partial lists ----------------
__global__ __launch_bounds__(256) void k_tkmerge(
    const float* __restrict__ pval, const int* __restrict__ pidx,
    int* __restrict__ tk)
{
    const int r = blockIdx.x*256 + threadIdx.x;
    if (r >= NROWS) return;
    const float* va = &pval[(size_t)r*20];
    const int*   ia = &pidx[(size_t)r*20];
    const float* vb = va + 10;
    const int*   ib = ia + 10;
    const int base = (r / NPTS) * NPTS;
    int* op = &tk[(size_t)r*NK];
    int pa = 0, pb = 0;
    #pragma unroll
    for (int s = 0; s < NK; ++s) {
        const float A = va[pa], Bv = vb[pb];
        const int  Ai = ia[pa], Bi = ib[pb];
        const bool ta = (A > Bv) || (A == Bv && Ai < Bi);
        op[s] = base + (ta ? Ai : Bi);
        pa += ta ? 1 : 0; pb += ta ? 0 : 1;
    }
}

// ---------------- Kernel D: fused tail (MFMA phase 2, unchanged) ----------------
#define AST 136
__global__ __launch_bounds__(256, 2) void k_fused(
    const float* __restrict__ x,
    const int* __restrict__ nb, const int* __restrict__ tk,
    const float* __restrict__ T1r, const float* __restrict__ P, const float* __restrict__ Q,
    const float* __restrict__ tW2, const float* __restrict__ tb2,
    const float* __restrict__ sW2, const float* __restrict__ sb2,
    const _Float16* __restrict__ wt3h, const _Float16* __restrict__ ws3h,
    const float* __restrict__ tb3, const float* __restrict__ sb3,
    float* __restrict__ out)
{
    __shared__ __align__(16) _Float16 A16[144*AST];
    __shared__ float Ssm[8][260];
    __shared__ float Zr[8][260];

    const int t  = threadIdx.x;
    const int r0 = blockIdx.x * 8;
    const int bb = r0 / NPTS;
    const int n0 = r0 % NPTS;

    {
        const float4 z4 = make_float4(0.f,0.f,0.f,0.f);
        float4* p4 = (float4*)A16;
        #pragma unroll
        for (int i = 0; i < 10; ++i) {
            const int idx = t + i*256;
            if (idx < 2448) p4[idx] = z4;
        }
    }
    __syncthreads();

    {
        const int o    = t & 127;
        const int half = t >> 7;
        const int g4   = o & ~3;

        const float4 f0 = *(const float4*)&tW2[o*12];
        const float4 f1 = *(const float4*)&tW2[o*12 + 4];
        const float4 f2 = *(const float4*)&tW2[o*12 + 8];
        const float4 wt0 = make_float4(f0.x, f0.w, f1.z, f2.y);
        const float4 wt1 = make_float4(f0.y, f1.x, f1.w, f2.z);
        const float4 wt2 = make_float4(f0.z, f1.y, f2.x, f2.w);
        const float4 wsw = *(const float4*)&sW2[o*4];
        const float tb2o = tb2[o], sb2o = sb2[o];

        #pragma unroll
        for (int ptl = 0; ptl < 4; ++ptl) {
            const int pt = half*4 + ptl;
            const int r  = r0 + pt;
            const int nb0 = nb[r*3+0], nb1 = nb[r*3+1], nb2 = nb[r*3+2];
            int ki[NK];
            #pragma unroll
            for (int k = 0; k < NK; ++k) ki[k] = tk[r*NK + k];
            const float4 h0 = *(const float4*)&T1r[(size_t)nb0*NW + g4];
            const float4 h1 = *(const float4*)&T1r[(size_t)nb1*NW + g4];
            const float4 h2 = *(const float4*)&T1r[(size_t)nb2*NW + g4];
            const float4 qf = *(const float4*)&Q[(size_t)r*NW + g4];
            float4 pf[NK];
            #pragma unroll
            for (int k = 0; k < NK; ++k) pf[k] = *(const float4*)&P[(size_t)ki[k]*NW + g4];

            const float z = tb2o + dot4(wt0,h0) + dot4(wt1,h1) + dot4(wt2,h2);
            A16[(128 + pt)*AST + o] = (_Float16)fmaxf(z, 0.f);
            #pragma unroll
            for (int k = 0; k < NK; ++k) {
                const float4 g1 = relu4(add4(pf[k], qf));
                A16[(pt*16 + k)*AST + o] = (_Float16)fmaxf(dot4(wsw, g1) + sb2o, 0.f);
            }
        }
    }
    __syncthreads();

    const int lane = t & 63, w = t >> 6;
    const int lr = lane & 15, lg = lane >> 4;
    const int n0w = w * 64;

    f32x4 accG[8][4] = {};
    f32x4 accZ[4] = {};

    #pragma unroll
    for (int kt = 0; kt < 4; ++kt) {
        const int ko = kt*32 + lg*8;
        f16x8 bs[4], bt[4];
        #pragma unroll
        for (int nt = 0; nt < 4; ++nt) {
            const int n = n0w + nt*16 + lr;
            bs[nt] = *(const f16x8*)&ws3h[n*NW + ko];
            bt[nt] = *(const f16x8*)&wt3h[n*NW + ko];
        }
        #pragma unroll
        for (int mt = 0; mt < 8; ++mt) {
            const f16x8 a = *(const f16x8*)&A16[(mt*16 + lr)*AST + ko];
            #pragma unroll
            for (int nt = 0; nt < 4; ++nt)
                accG[mt][nt] = __builtin_amdgcn_mfma_f32_16x16x32_f16(a, bs[nt], accG[mt][nt], 0,0,0);
        }
        const f16x8 az = *(const f16x8*)&A16[(128 + lr)*AST + ko];
        #pragma unroll
        for (int nt = 0; nt < 4; ++nt)
            accZ[nt] = __builtin_amdgcn_mfma_f32_16x16x32_f16(az, bt[nt], accZ[nt], 0,0,0);
    }

    const int rg = lg;
    #pragma unroll
    for (int mt = 0; mt < 8; ++mt) {
        #pragma unroll
        for (int nt = 0; nt < 4; ++nt) {
            float v;
            if (rg < 2)       v = fmaxf(fmaxf(accG[mt][nt][0], accG[mt][nt][1]),
                                        fmaxf(accG[mt][nt][2], accG[mt][nt][3]));
            else if (rg == 2) v = fmaxf(accG[mt][nt][0], accG[mt][nt][1]);
            else              v = -3.0e38f;
            v = fmaxf(v, __shfl_xor(v, 16));
            v = fmaxf(v, __shfl_xor(v, 32));
            if (lane < 16) Ssm[mt][n0w + nt*16 + lane] = v;
        }
    }
    #pragma unroll
    for (int nt = 0; nt < 4; ++nt) {
        #pragma unroll
        for (int q = 0; q < 4; ++q) {
            if (rg < 2) Zr[rg*4 + q][n0w + nt*16 + lr] = accZ[nt][q];
        }
    }
    __syncthreads();

    {
        const int c = t;
        const float tb = tb3[c], sb = sb3[c];
        const size_t go = ((size_t)bb*NC + c)*NPTS + n0;
        const float4 xv0 = *(const float4*)&x[go];
        const float4 xv1 = *(const float4*)&x[go + 4];
        const float xr[8] = {xv0.x,xv0.y,xv0.z,xv0.w, xv1.x,xv1.y,xv1.z,xv1.w};
        float ov[8];
        #pragma unroll
        for (int p = 0; p < 8; ++p)
            ov[p] = fmaxf(Zr[p][c] + tb + Ssm[p][c] + sb + xr[p], 0.f);
        *(float4*)&out[go]     = make_float4(ov[0],ov[1],ov[2],ov[3]);
        *(float4*)&out[go + 4] = make_float4(ov[4],ov[5],ov[6],ov[7]);
    }
}

extern "C" void kernel_launch(void* const* d_in, const int* in_sizes, int n_in,
                              void* d_out, int out_size, void* d_ws, size_t ws_size,
                              hipStream_t stream) {
    (void)in_sizes; (void)n_in; (void)out_size; (void)ws_size;
    const float* x   = (const float*)d_in[0];
    const int*   nb  = (const int*)d_in[2];
    const float* tW1 = (const float*)d_in[3];
    const float* tb1 = (const float*)d_in[4];
    const float* tW2 = (const float*)d_in[5];
    const float* tb2 = (const float*)d_in[6];
    const float* tW3 = (const float*)d_in[7];
    const float* tb3 = (const float*)d_in[8];
    const float* sW1 = (const float*)d_in[9];
    const float* sb1 = (const float*)d_in[10];
    const float* sW2 = (const float*)d_in[11];
    const float* sb2 = (const float*)d_in[12];
    const float* sW3 = (const float*)d_in[13];
    const float* sb3 = (const float*)d_in[14];
    float* out = (float*)d_out;

    float* ws  = (float*)d_ws;
    float* T1r  = ws;                       // 2,048,000 f32
    float* P    = ws + 2048000;             // 2,048,000 f32
    float* Q    = ws + 4096000;             // 2,048,000 f32
    float* xxp  = ws + 6144000;             // 16,000 f32
    int*   tk   = (int*)(ws + 6160000);     // 160,000 int
    float* pval = ws + 6320000;             // 320,000 f32
    int*   pidx = (int*)(ws + 6640000);     // 320,000 int
    _Float16* xb   = (_Float16*)(ws + 6960000);   // 8,388,608 f16
    _Float16* wt3h = xb + (size_t)NBATCH * 16 * PL2;
    _Float16* ws3h = wt3h + NC * NW;

    k_prep<<<NBATCH * 32, 256, 0, stream>>>(x, xb, xxp);
    k_wprep<<<32, 256, 0, stream>>>(tW3, wt3h, NC * NW);
    k_wprep<<<32, 256, 0, stream>>>(sW3, ws3h, NC * NW);
    k_rowgemm<<<dim3(NROWS / 32, 3), 256, 0, stream>>>(x, tW1, tb1, sW1, sb1, T1r, P, Q);
    k_topk<<<1024, 64, 0, stream>>>(xb, xxp, pval, pidx);
    k_tkmerge<<<(NROWS + 255) / 256, 256, 0, stream>>>(pval, pidx, tk);
    k_fused<<<NROWS / 8, 256, 0, stream>>>(x, nb, tk, T1r, P, Q,
                                           tW2, tb2, sW2, sb2, wt3h, ws3h, tb3, sb3, out);
}

// Round 8
// 469.778 us; speedup vs baseline: 1.3868x; 1.3868x over previous
//
#include <hip/hip_runtime.h>

#define NPTS 2000
#define NBATCH 8
#define NC 256
#define NW 128
#define NK 10
#define NROWS (NBATCH * NPTS)
#define JPAD 2048
#define PL2 (JPAD * 32)            // f16 elems per (b,kc,hl) plane

typedef _Float16 f16x8 __attribute__((ext_vector_type(8)));
typedef _Float16 f16x4 __attribute__((ext_vector_type(4)));
typedef float f32x4 __attribute__((ext_vector_type(4)));

__device__ __forceinline__ float dot4(float4 a, float4 b) {
    return a.x*b.x + a.y*b.y + a.z*b.z + a.w*b.w;
}
__device__ __forceinline__ float4 relu4(float4 a) {
    return make_float4(fmaxf(a.x,0.f), fmaxf(a.y,0.f), fmaxf(a.z,0.f), fmaxf(a.w,0.f));
}
__device__ __forceinline__ float4 add4(float4 a, float4 b) {
    return make_float4(a.x+b.x, a.y+b.y, a.z+b.z, a.w+b.w);
}

__device__ __forceinline__ void ins10(float d, int j, float* vals, int* idxs) {
    if (d > vals[9]) {
        float v = d; int id = j;
        #pragma unroll
        for (int s = 0; s < 10; ++s) {
            if (v > vals[s]) {
                float tv = vals[s]; vals[s] = v; v = tv;
                int   ti = idxs[s]; idxs[s] = id; id = ti;
            }
        }
    }
}

__device__ __forceinline__ void gl_lds16(const void* g, void* l) {
    __builtin_amdgcn_global_load_lds(
        (const __attribute__((address_space(1))) void*)g,
        (__attribute__((address_space(3))) void*)l, 16, 0, 0);
}

// ---------------- Kernel P: transpose to planar f16 hi/lo + row norms ----------------
// xb: [b][kc(8)][hl(2)][2048 j][32 c] f16. Rows >= NPTS zero-filled.
__global__ __launch_bounds__(256) void k_prep(
    const float* __restrict__ x, _Float16* __restrict__ xb,
    float* __restrict__ xx)
{
    __shared__ float T[64][259];
    __shared__ float Pp[64][4];
    const int t  = threadIdx.x;
    const int b  = blockIdx.x >> 5;
    const int n0 = (blockIdx.x & 31) * 64;

    #pragma unroll
    for (int p = 0; p < 64; ++p) {
        const int idx = p*256 + t;
        const int c = idx >> 6, nl = idx & 63;
        T[nl][c] = x[((size_t)b*NC + c)*NPTS + min(n0 + nl, NPTS-1)];
    }
    __syncthreads();

    const int row = t & 63, q = t >> 6;
    const int gr  = n0 + row;
    const bool ok = gr < NPTS;
    float ss = 0.f;
    #pragma unroll
    for (int u = 0; u < 2; ++u) {
        const int kc = 2*q + u;
        const size_t bh = ((size_t)(b*8 + kc)*2    )*PL2 + (size_t)gr*32;
        const size_t bl = ((size_t)(b*8 + kc)*2 + 1)*PL2 + (size_t)gr*32;
        #pragma unroll
        for (int g = 0; g < 4; ++g) {
            f16x8 vh, vl;
            #pragma unroll
            for (int e = 0; e < 8; ++e) {
                const float f = ok ? T[row][kc*32 + g*8 + e] : 0.f;
                ss = fmaf(f, f, ss);
                const _Float16 h = (_Float16)f;
                vh[e] = h;
                vl[e] = (_Float16)(f - (float)h);
            }
            *(f16x8*)&xb[bh + g*8] = vh;
            *(f16x8*)&xb[bl + g*8] = vl;
        }
    }
    Pp[row][q] = ss;
    __syncthreads();
    if (t < 64 && n0 + t < NPTS)
        xx[(size_t)b*NPTS + n0 + t] = Pp[t][0] + Pp[t][1] + Pp[t][2] + Pp[t][3];
}

// ---------------- Kernel W: f32 -> f16 weight conversion ----------------
__global__ __launch_bounds__(256) void k_wprep(const float* __restrict__ a,
                                               _Float16* __restrict__ o, int n)
{
    const int i = (blockIdx.x*256 + threadIdx.x)*4;
    if (i < n) {
        const float4 v = *(const float4*)&a[i];
        f16x4 h = {(_Float16)v.x, (_Float16)v.y, (_Float16)v.z, (_Float16)v.w};
        *(f16x4*)&o[i] = h;
    }
}

// ---------------- Kernel A: row GEMM -> T1r / P / Q (unchanged) ----------------
__global__ __launch_bounds__(256) void k_rowgemm(
    const float* __restrict__ x,
    const float* __restrict__ tW1, const float* __restrict__ tb1,
    const float* __restrict__ sW1, const float* __restrict__ sb1,
    float* __restrict__ T1r, float* __restrict__ P, float* __restrict__ Q)
{
    __shared__ float Xs[32][34];
    __shared__ float Ws[32][132];
    const int t  = threadIdx.x;
    const int r0 = blockIdx.x * 32;
    const int sel = blockIdx.y;
    const int jq = t & 15,  iq = t >> 4;
    const int j0 = jq * 8,  i0 = iq * 2;

    float acc[2][8];
    #pragma unroll
    for (int a = 0; a < 2; ++a)
        #pragma unroll
        for (int q = 0; q < 8; ++q) acc[a][q] = 0.f;

    const int li = t & 31;
    const int lk = t >> 5;
    const int rl = r0 + li;
    const int lb = rl / NPTS, ln = rl % NPTS;

    for (int c0 = 0; c0 < NC; c0 += 32) {
        #pragma unroll
        for (int p = 0; p < 4; ++p) {
            int kk = lk + p * 8;
            Xs[kk][li] = x[((size_t)lb * NC + c0 + kk) * NPTS + ln];
        }
        #pragma unroll
        for (int jj = 0; jj < 16; ++jj) {
            int j = jj * 8 + lk;
            int c = c0 + li;
            float w;
            if (sel == 0)      w = tW1[j * NC + c];
            else if (sel == 1) w = sW1[j * (2*NC) + c];
            else               w = sW1[j * (2*NC) + NC + c];
            Ws[li][j] = w;
        }
        __syncthreads();
        #pragma unroll 8
        for (int kk = 0; kk < 32; ++kk) {
            const float2 xv = *(const float2*)&Xs[kk][i0];
            const float4 w0 = *(const float4*)&Ws[kk][j0];
            const float4 w1 = *(const float4*)&Ws[kk][j0 + 4];
            float w[8] = {w0.x,w0.y,w0.z,w0.w,w1.x,w1.y,w1.z,w1.w};
            #pragma unroll
            for (int q = 0; q < 8; ++q) {
                acc[0][q] = fmaf(xv.x, w[q], acc[0][q]);
                acc[1][q] = fmaf(xv.y, w[q], acc[1][q]);
            }
        }
        __syncthreads();
    }

    #pragma unroll
    for (int a = 0; a < 2; ++a) {
        const int r = r0 + i0 + a;
        float o[8];
        #pragma unroll
        for (int q = 0; q < 8; ++q) {
            float v = acc[a][q];
            if (sel == 0)      { v += tb1[j0+q]; v = fmaxf(v, 0.f); }
            else if (sel == 2) { v += sb1[j0+q]; }
            o[q] = v;
        }
        float* dst = (sel==0 ? T1r : (sel==1 ? P : Q)) + (size_t)r * NW + j0;
        *(float4*)dst       = make_float4(o[0],o[1],o[2],o[3]);
        *(float4*)(dst + 4) = make_float4(o[4],o[5],o[6],o[7]);
    }
}

// ---------------- Kernel B v6: 4-wave blocks, 128 reg-resident i-rows, LDS-shared j ----------------
// Wave w owns i rows [ig*128 + w*32, +32) in regs (B operand). j-quarter streamed via
// DMA'd LDS 16-j tiles (16 KB, double-buffered), shared across the 4 waves (A operand).
// One barrier per tile. In-register top-10, in-LDS 4-list merge, partials to pval/pidx.
__global__ __launch_bounds__(256, 2) void k_topk(
    const _Float16* __restrict__ xb, const float* __restrict__ xx,
    float* __restrict__ pval, int* __restrict__ pidx)
{
    __shared__ __align__(16) char smem[40960];   // 2x16KB staging | 20KB+20KB merge overlay

    const int t    = threadIdx.x;
    const int b    = blockIdx.x & 7;             // batch -> XCD
    const int ig   = (blockIdx.x >> 3) & 15;
    const int jq   = blockIdx.x >> 7;            // 0..3
    const int i0   = ig * 128;
    const int lane = t & 63;
    const int w    = t >> 6;
    const int lr   = lane & 15, rg = lane >> 4;
    const size_t bb = (size_t)b * 16 * PL2;      // f16 elems

    // resident B-fragments: 2 i-tiles x 8 kc x (hi,lo) = 128 VGPR
    f16x8 bh[2][8], bl[2][8];
    #pragma unroll
    for (int it = 0; it < 2; ++it) {
        const int i = min(i0 + w*32 + it*16 + lr, NPTS - 1);
        #pragma unroll
        for (int kc = 0; kc < 8; ++kc) {
            const size_t ph = bb + (size_t)(kc*2)*PL2 + (size_t)i*32 + rg*8;
            bh[it][kc] = *(const f16x8*)&xb[ph];
            bl[it][kc] = *(const f16x8*)&xb[ph + PL2];
        }
    }

    float v0[10], v1[10]; int x0[10], x1[10];
    #pragma unroll
    for (int s = 0; s < 10; ++s) { v0[s]=v1[s]=-3.0e38f; x0[s]=x1[s]=0x7fffffff; }

    const float* xxp = xx + (size_t)b * NPTS;
    const char*  gb  = (const char*)xb + bb*2;   // batch base, bytes
    const int jbase = jq * 512;

    // staging: plane p (=kc*2+hl) is 1KB per 16-j tile; wave stages planes w*4..w*4+3
    // prologue: tile 0 -> buf 0
    #pragma unroll
    for (int q = 0; q < 4; ++q) {
        const int p = w*4 + q;
        gl_lds16(gb + (size_t)p*(PL2*2) + (size_t)jbase*64 + lane*16,
                 smem + p*1024);
    }

    f32x4 acc0, acc1;
    for (int jt = 0; jt < 32; ++jt) {
        __syncthreads();   // buf[jt&1] DMA complete; all waves done with buf[(jt+1)&1]

        if (jt < 31) {     // prefetch next tile into the other buffer
            const int j0n = jbase + (jt+1)*16;
            char* ld = smem + ((jt+1) & 1)*16384;
            #pragma unroll
            for (int q = 0; q < 4; ++q) {
                const int p = w*4 + q;
                gl_lds16(gb + (size_t)p*(PL2*2) + (size_t)j0n*64 + lane*16,
                         ld + p*1024);
            }
        }

        // compute on buf[jt&1]: A = j-tile from LDS, B = resident i-frags
        acc0 = (f32x4){0.f,0.f,0.f,0.f};
        acc1 = (f32x4){0.f,0.f,0.f,0.f};
        {
            const char* Bb = smem + (jt & 1)*16384;
            const int ao = lr*64 + rg*16;
            #pragma unroll
            for (int kc = 0; kc < 8; ++kc) {
                const f16x8 ah = *(const f16x8*)(Bb + (kc*2    )*1024 + ao);
                const f16x8 al = *(const f16x8*)(Bb + (kc*2 + 1)*1024 + ao);
                acc0 = __builtin_amdgcn_mfma_f32_16x16x32_f16(ah, bh[0][kc], acc0, 0,0,0);
                acc1 = __builtin_amdgcn_mfma_f32_16x16x32_f16(ah, bh[1][kc], acc1, 0,0,0);
                acc0 = __builtin_amdgcn_mfma_f32_16x16x32_f16(ah, bl[0][kc], acc0, 0,0,0);
                acc1 = __builtin_amdgcn_mfma_f32_16x16x32_f16(ah, bl[1][kc], acc1, 0,0,0);
                acc0 = __builtin_amdgcn_mfma_f32_16x16x32_f16(al, bh[0][kc], acc0, 0,0,0);
                acc1 = __builtin_amdgcn_mfma_f32_16x16x32_f16(al, bh[1][kc], acc1, 0,0,0);
            }
        }

        // selection: lane's i-col = lr (per tile); j rows = rg*4+q, ascending
        {
            const int j0r = jbase + jt*16 + rg*4;
            const f32x4 xv = *(const f32x4*)&xxp[min(j0r, NPTS-4)];
            #pragma unroll
            for (int q = 0; q < 4; ++q) {
                const int j = j0r + q;
                if (j < NPTS) {
                    ins10(2.f*acc0[q] - xv[q], j, v0, x0);
                    ins10(2.f*acc1[q] - xv[q], j, v1, x1);
                }
            }
        }
    }

    // ---- in-block merge: 4 rg-lists per (w,it,lr) ----
    __syncthreads();
    float* mval = (float*)smem;
    int*   midx = (int*)(smem + 20480);
    {
        const int g0 = (w*2 + 0)*16 + lr;   // group id = local i
        const int g1 = (w*2 + 1)*16 + lr;
        #pragma unroll
        for (int s = 0; s < 10; ++s) {
            mval[(g0*4 + rg)*10 + s] = v0[s];  midx[(g0*4 + rg)*10 + s] = x0[s];
            mval[(g1*4 + rg)*10 + s] = v1[s];  midx[(g1*4 + rg)*10 + s] = x1[s];
        }
    }
    __syncthreads();
    {   // step 1: 256 workers merge (pr, pr+2) -> pr  for pr in {0,1} of each group
        const int g = t >> 1, pr = t & 1;
        float* va = &mval[(g*4 + pr)*10];     int* ia = &midx[(g*4 + pr)*10];
        const float* vb = &mval[(g*4 + pr + 2)*10]; const int* ib = &midx[(g*4 + pr + 2)*10];
        float ov[10]; int oi[10]; int pa = 0, pb = 0;
        #pragma unroll
        for (int s = 0; s < 10; ++s) {
            const float A = va[pa], Bv = vb[pb];
            const int  Ai = ia[pa], Bi = ib[pb];
            const bool ta = (A > Bv) || (A == Bv && Ai < Bi);
            ov[s] = ta ? A : Bv; oi[s] = ta ? Ai : Bi;
            pa += ta ? 1 : 0; pb += ta ? 0 : 1;
        }
        #pragma unroll
        for (int s = 0; s < 10; ++s) { va[s] = ov[s]; ia[s] = oi[s]; }
    }
    __syncthreads();
    if (t < 128) {   // step 2: final merge per group + write partial
        const int g = t;
        const int i = i0 + g;
        if (i < NPTS) {
            const float* va = &mval[(g*4 + 0)*10]; const int* ia = &midx[(g*4 + 0)*10];
            const float* vb = &mval[(g*4 + 1)*10]; const int* ib = &midx[(g*4 + 1)*10];
            float* ov = &pval[((size_t)(b*NPTS + i)*4 + jq)*10];
            int*   oi = &pidx[((size_t)(b*NPTS + i)*4 + jq)*10];
            int pa = 0, pb = 0;
            #pragma unroll
            for (int s = 0; s < 10; ++s) {
                const float A = va[pa], Bv = vb[pb];
                const int  Ai = ia[pa], Bi = ib[pb];
                const bool ta = (A > Bv) || (A == Bv && Ai < Bi);
                ov[s] = ta ? A : Bv; oi[s] = ta ? Ai : Bi;
                pa += ta ? 1 : 0; pb += ta ? 0 : 1;
            }
        }
    }
}

// ---------------- Kernel M: 4-way heads-merge of j-quarter partials ----------------
__global__ __launch_bounds__(256) void k_tkmerge(
    const float* __restrict__ pval, const int* __restrict__ pidx,
    int* __restrict__ tk)
{
    const int r = blockIdx.x*256 + threadIdx.x;
    if (r >= NROWS) return;
    const float* v  = &pval[(size_t)r*40];
    const int*   ix = &pidx[(size_t)r*40];
    const int base = (r / NPTS) * NPTS;
    int* op = &tk[(size_t)r*NK];
    int p0 = 0, p1 = 0, p2 = 0, p3 = 0;
    #pragma unroll
    for (int s = 0; s < NK; ++s) {
        float bv = -3.4e38f; int bi = 0x7fffffff; int bl = 0;
        {
            const float vv = v[p0];       const int ii = ix[p0];
            if (vv > bv || (vv == bv && ii < bi)) { bv = vv; bi = ii; bl = 0; }
        }
        {
            const float vv = v[10 + p1];  const int ii = ix[10 + p1];
            if (vv > bv || (vv == bv && ii < bi)) { bv = vv; bi = ii; bl = 1; }
        }
        {
            const float vv = v[20 + p2];  const int ii = ix[20 + p2];
            if (vv > bv || (vv == bv && ii < bi)) { bv = vv; bi = ii; bl = 2; }
        }
        {
            const float vv = v[30 + p3];  const int ii = ix[30 + p3];
            if (vv > bv || (vv == bv && ii < bi)) { bv = vv; bi = ii; bl = 3; }
        }
        p0 += (bl == 0); p1 += (bl == 1); p2 += (bl == 2); p3 += (bl == 3);
        op[s] = base + bi;
    }
}

// ---------------- Kernel D: fused tail (MFMA phase 2, unchanged) ----------------
#define AST 136
__global__ __launch_bounds__(256, 2) void k_fused(
    const float* __restrict__ x,
    const int* __restrict__ nb, const int* __restrict__ tk,
    const float* __restrict__ T1r, const float* __restrict__ P, const float* __restrict__ Q,
    const float* __restrict__ tW2, const float* __restrict__ tb2,
    const float* __restrict__ sW2, const float* __restrict__ sb2,
    const _Float16* __restrict__ wt3h, const _Float16* __restrict__ ws3h,
    const float* __restrict__ tb3, const float* __restrict__ sb3,
    float* __restrict__ out)
{
    __shared__ __align__(16) _Float16 A16[144*AST];
    __shared__ float Ssm[8][260];
    __shared__ float Zr[8][260];

    const int t  = threadIdx.x;
    const int r0 = blockIdx.x * 8;
    const int bb = r0 / NPTS;
    const int n0 = r0 % NPTS;

    {
        const float4 z4 = make_float4(0.f,0.f,0.f,0.f);
        float4* p4 = (float4*)A16;
        #pragma unroll
        for (int i = 0; i < 10; ++i) {
            const int idx = t + i*256;
            if (idx < 2448) p4[idx] = z4;
        }
    }
    __syncthreads();

    {
        const int o    = t & 127;
        const int half = t >> 7;
        const int g4   = o & ~3;

        const float4 f0 = *(const float4*)&tW2[o*12];
        const float4 f1 = *(const float4*)&tW2[o*12 + 4];
        const float4 f2 = *(const float4*)&tW2[o*12 + 8];
        const float4 wt0 = make_float4(f0.x, f0.w, f1.z, f2.y);
        const float4 wt1 = make_float4(f0.y, f1.x, f1.w, f2.z);
        const float4 wt2 = make_float4(f0.z, f1.y, f2.x, f2.w);
        const float4 wsw = *(const float4*)&sW2[o*4];
        const float tb2o = tb2[o], sb2o = sb2[o];

        #pragma unroll
        for (int ptl = 0; ptl < 4; ++ptl) {
            const int pt = half*4 + ptl;
            const int r  = r0 + pt;
            const int nb0 = nb[r*3+0], nb1 = nb[r*3+1], nb2 = nb[r*3+2];
            int ki[NK];
            #pragma unroll
            for (int k = 0; k < NK; ++k) ki[k] = tk[r*NK + k];
            const float4 h0 = *(const float4*)&T1r[(size_t)nb0*NW + g4];
            const float4 h1 = *(const float4*)&T1r[(size_t)nb1*NW + g4];
            const float4 h2 = *(const float4*)&T1r[(size_t)nb2*NW + g4];
            const float4 qf = *(const float4*)&Q[(size_t)r*NW + g4];
            float4 pf[NK];
            #pragma unroll
            for (int k = 0; k < NK; ++k) pf[k] = *(const float4*)&P[(size_t)ki[k]*NW + g4];

            const float z = tb2o + dot4(wt0,h0) + dot4(wt1,h1) + dot4(wt2,h2);
            A16[(128 + pt)*AST + o] = (_Float16)fmaxf(z, 0.f);
            #pragma unroll
            for (int k = 0; k < NK; ++k) {
                const float4 g1 = relu4(add4(pf[k], qf));
                A16[(pt*16 + k)*AST + o] = (_Float16)fmaxf(dot4(wsw, g1) + sb2o, 0.f);
            }
        }
    }
    __syncthreads();

    const int lane = t & 63, w = t >> 6;
    const int lr = lane & 15, lg = lane >> 4;
    const int n0w = w * 64;

    f32x4 accG[8][4] = {};
    f32x4 accZ[4] = {};

    #pragma unroll
    for (int kt = 0; kt < 4; ++kt) {
        const int ko = kt*32 + lg*8;
        f16x8 bs[4], bt[4];
        #pragma unroll
        for (int nt = 0; nt < 4; ++nt) {
            const int n = n0w + nt*16 + lr;
            bs[nt] = *(const f16x8*)&ws3h[n*NW + ko];
            bt[nt] = *(const f16x8*)&wt3h[n*NW + ko];
        }
        #pragma unroll
        for (int mt = 0; mt < 8; ++mt) {
            const f16x8 a = *(const f16x8*)&A16[(mt*16 + lr)*AST + ko];
            #pragma unroll
            for (int nt = 0; nt < 4; ++nt)
                accG[mt][nt] = __builtin_amdgcn_mfma_f32_16x16x32_f16(a, bs[nt], accG[mt][nt], 0,0,0);
        }
        const f16x8 az = *(const f16x8*)&A16[(128 + lr)*AST + ko];
        #pragma unroll
        for (int nt = 0; nt < 4; ++nt)
            accZ[nt] = __builtin_amdgcn_mfma_f32_16x16x32_f16(az, bt[nt], accZ[nt], 0,0,0);
    }

    const int rg = lg;
    #pragma unroll
    for (int mt = 0; mt < 8; ++mt) {
        #pragma unroll
        for (int nt = 0; nt < 4; ++nt) {
            float v;
            if (rg < 2)       v = fmaxf(fmaxf(accG[mt][nt][0], accG[mt][nt][1]),
                                        fmaxf(accG[mt][nt][2], accG[mt][nt][3]));
            else if (rg == 2) v = fmaxf(accG[mt][nt][0], accG[mt][nt][1]);
            else              v = -3.0e38f;
            v = fmaxf(v, __shfl_xor(v, 16));
            v = fmaxf(v, __shfl_xor(v, 32));
            if (lane < 16) Ssm[mt][n0w + nt*16 + lane] = v;
        }
    }
    #pragma unroll
    for (int nt = 0; nt < 4; ++nt) {
        #pragma unroll
        for (int q = 0; q < 4; ++q) {
            if (rg < 2) Zr[rg*4 + q][n0w + nt*16 + lr] = accZ[nt][q];
        }
    }
    __syncthreads();

    {
        const int c = t;
        const float tb = tb3[c], sb = sb3[c];
        const size_t go = ((size_t)bb*NC + c)*NPTS + n0;
        const float4 xv0 = *(const float4*)&x[go];
        const float4 xv1 = *(const float4*)&x[go + 4];
        const float xr[8] = {xv0.x,xv0.y,xv0.z,xv0.w, xv1.x,xv1.y,xv1.z,xv1.w};
        float ov[8];
        #pragma unroll
        for (int p = 0; p < 8; ++p)
            ov[p] = fmaxf(Zr[p][c] + tb + Ssm[p][c] + sb + xr[p], 0.f);
        *(float4*)&out[go]     = make_float4(ov[0],ov[1],ov[2],ov[3]);
        *(float4*)&out[go + 4] = make_float4(ov[4],ov[5],ov[6],ov[7]);
    }
}

extern "C" void kernel_launch(void* const* d_in, const int* in_sizes, int n_in,
                              void* d_out, int out_size, void* d_ws, size_t ws_size,
                              hipStream_t stream) {
    (void)in_sizes; (void)n_in; (void)out_size; (void)ws_size;
    const float* x   = (const float*)d_in[0];
    const int*   nb  = (const int*)d_in[2];
    const float* tW1 = (const float*)d_in[3];
    const float* tb1 = (const float*)d_in[4];
    const float* tW2 = (const float*)d_in[5];
    const float* tb2 = (const float*)d_in[6];
    const float* tW3 = (const float*)d_in[7];
    const float* tb3 = (const float*)d_in[8];
    const float* sW1 = (const float*)d_in[9];
    const float* sb1 = (const float*)d_in[10];
    const float* sW2 = (const float*)d_in[11];
    const float* sb2 = (const float*)d_in[12];
    const float* sW3 = (const float*)d_in[13];
    const float* sb3 = (const float*)d_in[14];
    float* out = (float*)d_out;

    float* ws  = (float*)d_ws;
    float* T1r  = ws;                       // 2,048,000 f32
    float* P    = ws + 2048000;             // 2,048,000 f32
    float* Q    = ws + 4096000;             // 2,048,000 f32
    float* xxp  = ws + 6144000;             // 16,000 f32
    int*   tk   = (int*)(ws + 6160000);     // 160,000 int
    float* pval = ws + 6320000;             // 640,000 f32
    int*   pidx = (int*)(ws + 6960000);     // 640,000 int
    _Float16* xb   = (_Float16*)(ws + 7600000);   // 8,388,608 f16
    _Float16* wt3h = xb + (size_t)NBATCH * 16 * PL2;
    _Float16* ws3h = wt3h + NC * NW;

    k_prep<<<NBATCH * 32, 256, 0, stream>>>(x, xb, xxp);
    k_wprep<<<32, 256, 0, stream>>>(tW3, wt3h, NC * NW);
    k_wprep<<<32, 256, 0, stream>>>(sW3, ws3h, NC * NW);
    k_rowgemm<<<dim3(NROWS / 32, 3), 256, 0, stream>>>(x, tW1, tb1, sW1, sb1, T1r, P, Q);
    k_topk<<<512, 256, 0, stream>>>(xb, xxp, pval, pidx);
    k_tkmerge<<<(NROWS + 255) / 256, 256, 0, stream>>>(pval, pidx, tk);
    k_fused<<<NROWS / 8, 256, 0, stream>>>(x, nb, tk, T1r, P, Q,
                                           tW2, tb2, sW2, sb2, wt3h, ws3h, tb3, sb3, out);
}

// Round 9
// 448.367 us; speedup vs baseline: 1.4530x; 1.0478x over previous
//
#include <hip/hip_runtime.h>

#define NPTS 2000
#define NBATCH 8
#define NC 256
#define NW 128
#define NK 10
#define NROWS (NBATCH * NPTS)
#define JPAD 2048
#define PL2 (JPAD * 32)            // f16 elems per (b,kc,hl) plane

typedef _Float16 f16x8 __attribute__((ext_vector_type(8)));
typedef _Float16 f16x4 __attribute__((ext_vector_type(4)));
typedef float f32x4 __attribute__((ext_vector_type(4)));

__device__ __forceinline__ float dot4(float4 a, float4 b) {
    return a.x*b.x + a.y*b.y + a.z*b.z + a.w*b.w;
}
__device__ __forceinline__ float4 relu4(float4 a) {
    return make_float4(fmaxf(a.x,0.f), fmaxf(a.y,0.f), fmaxf(a.z,0.f), fmaxf(a.w,0.f));
}
__device__ __forceinline__ float4 add4(float4 a, float4 b) {
    return make_float4(a.x+b.x, a.y+b.y, a.z+b.z, a.w+b.w);
}

__device__ __forceinline__ void ins10(float d, int j, float* vals, int* idxs) {
    if (d > vals[9]) {
        float v = d; int id = j;
        #pragma unroll
        for (int s = 0; s < 10; ++s) {
            if (v > vals[s]) {
                float tv = vals[s]; vals[s] = v; v = tv;
                int   ti = idxs[s]; idxs[s] = id; id = ti;
            }
        }
    }
}

__device__ __forceinline__ void gl_lds16(const void* g, void* l) {
    __builtin_amdgcn_global_load_lds(
        (const __attribute__((address_space(1))) void*)g,
        (__attribute__((address_space(3))) void*)l, 16, 0, 0);
}

// ---------------- Kernel P: transpose to planar f16 hi/lo (granule-swizzled) + norms ----------------
// xb: [b][kc(8)][hl(2)][2048 j][32 c] f16; within each row's 64B, c-granule g (8 f16)
// stored at slot g ^ ((j>>1)&3). Rows >= NPTS zero-filled.
__global__ __launch_bounds__(256) void k_prep(
    const float* __restrict__ x, _Float16* __restrict__ xb,
    float* __restrict__ xx)
{
    __shared__ float T[64][259];
    __shared__ float Pp[64][4];
    const int t  = threadIdx.x;
    const int b  = blockIdx.x >> 5;
    const int n0 = (blockIdx.x & 31) * 64;

    #pragma unroll
    for (int p = 0; p < 64; ++p) {
        const int idx = p*256 + t;
        const int c = idx >> 6, nl = idx & 63;
        T[nl][c] = x[((size_t)b*NC + c)*NPTS + min(n0 + nl, NPTS-1)];
    }
    __syncthreads();

    const int row = t & 63, q = t >> 6;
    const int gr  = n0 + row;
    const bool ok = gr < NPTS;
    const int sw  = (gr >> 1) & 3;
    float ss = 0.f;
    #pragma unroll
    for (int u = 0; u < 2; ++u) {
        const int kc = 2*q + u;
        const size_t bh = ((size_t)(b*8 + kc)*2    )*PL2 + (size_t)gr*32;
        const size_t bl = ((size_t)(b*8 + kc)*2 + 1)*PL2 + (size_t)gr*32;
        #pragma unroll
        for (int g = 0; g < 4; ++g) {
            f16x8 vh, vl;
            #pragma unroll
            for (int e = 0; e < 8; ++e) {
                const float f = ok ? T[row][kc*32 + g*8 + e] : 0.f;
                ss = fmaf(f, f, ss);
                const _Float16 h = (_Float16)f;
                vh[e] = h;
                vl[e] = (_Float16)(f - (float)h);
            }
            *(f16x8*)&xb[bh + (g ^ sw)*8] = vh;
            *(f16x8*)&xb[bl + (g ^ sw)*8] = vl;
        }
    }
    Pp[row][q] = ss;
    __syncthreads();
    if (t < 64 && n0 + t < NPTS)
        xx[(size_t)b*NPTS + n0 + t] = Pp[t][0] + Pp[t][1] + Pp[t][2] + Pp[t][3];
}

// ---------------- Kernel W: f32 -> f16 weight conversion ----------------
__global__ __launch_bounds__(256) void k_wprep(const float* __restrict__ a,
                                               _Float16* __restrict__ o, int n)
{
    const int i = (blockIdx.x*256 + threadIdx.x)*4;
    if (i < n) {
        const float4 v = *(const float4*)&a[i];
        f16x4 h = {(_Float16)v.x, (_Float16)v.y, (_Float16)v.z, (_Float16)v.w};
        *(f16x4*)&o[i] = h;
    }
}

// ---------------- Kernel A: row GEMM -> T1r / P / Q (unchanged) ----------------
__global__ __launch_bounds__(256) void k_rowgemm(
    const float* __restrict__ x,
    const float* __restrict__ tW1, const float* __restrict__ tb1,
    const float* __restrict__ sW1, const float* __restrict__ sb1,
    float* __restrict__ T1r, float* __restrict__ P, float* __restrict__ Q)
{
    __shared__ float Xs[32][34];
    __shared__ float Ws[32][132];
    const int t  = threadIdx.x;
    const int r0 = blockIdx.x * 32;
    const int sel = blockIdx.y;
    const int jq = t & 15,  iq = t >> 4;
    const int j0 = jq * 8,  i0 = iq * 2;

    float acc[2][8];
    #pragma unroll
    for (int a = 0; a < 2; ++a)
        #pragma unroll
        for (int q = 0; q < 8; ++q) acc[a][q] = 0.f;

    const int li = t & 31;
    const int lk = t >> 5;
    const int rl = r0 + li;
    const int lb = rl / NPTS, ln = rl % NPTS;

    for (int c0 = 0; c0 < NC; c0 += 32) {
        #pragma unroll
        for (int p = 0; p < 4; ++p) {
            int kk = lk + p * 8;
            Xs[kk][li] = x[((size_t)lb * NC + c0 + kk) * NPTS + ln];
        }
        #pragma unroll
        for (int jj = 0; jj < 16; ++jj) {
            int j = jj * 8 + lk;
            int c = c0 + li;
            float w;
            if (sel == 0)      w = tW1[j * NC + c];
            else if (sel == 1) w = sW1[j * (2*NC) + c];
            else               w = sW1[j * (2*NC) + NC + c];
            Ws[li][j] = w;
        }
        __syncthreads();
        #pragma unroll 8
        for (int kk = 0; kk < 32; ++kk) {
            const float2 xv = *(const float2*)&Xs[kk][i0];
            const float4 w0 = *(const float4*)&Ws[kk][j0];
            const float4 w1 = *(const float4*)&Ws[kk][j0 + 4];
            float w[8] = {w0.x,w0.y,w0.z,w0.w,w1.x,w1.y,w1.z,w1.w};
            #pragma unroll
            for (int q = 0; q < 8; ++q) {
                acc[0][q] = fmaf(xv.x, w[q], acc[0][q]);
                acc[1][q] = fmaf(xv.y, w[q], acc[1][q]);
            }
        }
        __syncthreads();
    }

    #pragma unroll
    for (int a = 0; a < 2; ++a) {
        const int r = r0 + i0 + a;
        float o[8];
        #pragma unroll
        for (int q = 0; q < 8; ++q) {
            float v = acc[a][q];
            if (sel == 0)      { v += tb1[j0+q]; v = fmaxf(v, 0.f); }
            else if (sel == 2) { v += sb1[j0+q]; }
            o[q] = v;
        }
        float* dst = (sel==0 ? T1r : (sel==1 ? P : Q)) + (size_t)r * NW + j0;
        *(float4*)dst       = make_float4(o[0],o[1],o[2],o[3]);
        *(float4*)(dst + 4) = make_float4(o[4],o[5],o[6],o[7]);
    }
}

// ---------------- Kernel B v7: low-pressure MFMA distance + reg top-10 ----------------
// Block = 4 waves x 16 i-rows = 64 i. Per lane: 16 resident frags (64 VGPR) + 1 list pair.
// j streamed via DMA'd 16KB tiles (16 planes x 1KB), double-buffered, shared by 4 waves.
// Conflict-free ds_read via pre-baked granule swizzle. Grid = 8b x 32ig x 3jh = 768.
__global__ __launch_bounds__(256, 3) void k_topk(
    const _Float16* __restrict__ xb, const float* __restrict__ xx,
    float* __restrict__ pval, int* __restrict__ pidx)
{
    __shared__ __align__(16) char smem[32768];

    const int t    = threadIdx.x;
    const int b    = blockIdx.x & 7;             // batch -> XCD
    const int ig   = (blockIdx.x >> 3) & 31;
    const int jh   = blockIdx.x >> 8;            // 0..2
    const int i0   = ig * 64;
    const int lane = t & 63;
    const int w    = t >> 6;
    const int lr   = lane & 15, rg = lane >> 4;
    const size_t bbase = (size_t)b * 16 * PL2;   // f16 elems

    // resident B-fragments: this wave's 16 i-rows, 8 kc x (hi,lo) = 64 VGPR
    f16x8 bh[8], bl[8];
    {
        const int i = min(i0 + w*16 + lr, NPTS - 1);
        const int sw = (i >> 1) & 3;
        const int go = (rg ^ sw) * 8;
        #pragma unroll
        for (int kc = 0; kc < 8; ++kc) {
            const size_t ph = bbase + (size_t)(kc*2)*PL2 + (size_t)i*32 + go;
            bh[kc] = *(const f16x8*)&xb[ph];
            bl[kc] = *(const f16x8*)&xb[ph + PL2];
        }
    }

    float vals[10]; int idxs[10];
    #pragma unroll
    for (int s = 0; s < 10; ++s) { vals[s] = -3.0e38f; idxs[s] = 0x7fffffff; }

    const float* xxp = xx + (size_t)b * NPTS;
    const char*  gb  = (const char*)xb + bbase*2;    // batch base, bytes

    // j-third tile ranges (125 tiles of 16 j total)
    const int jt0 = (jh == 0) ? 0 : (jh == 1 ? 42 : 84);
    const int jt1 = (jh == 0) ? 42 : (jh == 1 ? 84 : 125);

    // prologue: stage tile jt0 into buf jt0&1 (wave w stages planes 4w..4w+3)
    #pragma unroll
    for (int q = 0; q < 4; ++q) {
        const int p = w*4 + q;
        gl_lds16(gb + (size_t)p*(PL2*2) + (size_t)jt0*1024 + lane*16,
                 smem + ((jt0 & 1)*16384) + p*1024);
    }

    const int ao = lr*64 + ((rg ^ ((lr >> 1) & 3)) << 4);

    for (int jt = jt0; jt < jt1; ++jt) {
        __syncthreads();   // buf[jt&1] DMA complete; all waves done with buf[(jt&1)^1]

        if (jt + 1 < jt1) {   // prefetch next tile into the other buffer
            char* ld = smem + (((jt+1) & 1)*16384);
            #pragma unroll
            for (int q = 0; q < 4; ++q) {
                const int p = w*4 + q;
                gl_lds16(gb + (size_t)p*(PL2*2) + (size_t)(jt+1)*1024 + lane*16,
                         ld + p*1024);
            }
        }

        // compute on buf[jt&1]: A = j-tile (LDS), B = resident i-frags
        f32x4 acc = {0.f,0.f,0.f,0.f};
        {
            const char* Bb = smem + (jt & 1)*16384;
            #pragma unroll
            for (int kc = 0; kc < 8; ++kc) {
                const f16x8 ah = *(const f16x8*)(Bb + (kc*2    )*1024 + ao);
                const f16x8 al = *(const f16x8*)(Bb + (kc*2 + 1)*1024 + ao);
                acc = __builtin_amdgcn_mfma_f32_16x16x32_f16(ah, bh[kc], acc, 0,0,0);
                acc = __builtin_amdgcn_mfma_f32_16x16x32_f16(ah, bl[kc], acc, 0,0,0);
                acc = __builtin_amdgcn_mfma_f32_16x16x32_f16(al, bh[kc], acc, 0,0,0);
            }
        }

        // selection: lane's i-col = lr; j rows = jt*16 + rg*4 + q, ascending
        {
            const int j0r = jt*16 + rg*4;
            const f32x4 xv = *(const f32x4*)&xxp[j0r];
            const float d0 = 2.f*acc[0] - xv[0];
            const float d1 = 2.f*acc[1] - xv[1];
            const float d2 = 2.f*acc[2] - xv[2];
            const float d3 = 2.f*acc[3] - xv[3];
            const float mx = fmaxf(fmaxf(d0, d1), fmaxf(d2, d3));
            if (mx > vals[9]) {
                ins10(d0, j0r,     vals, idxs);
                ins10(d1, j0r + 1, vals, idxs);
                ins10(d2, j0r + 2, vals, idxs);
                ins10(d3, j0r + 3, vals, idxs);
            }
        }
    }

    // ---- in-block merge: 4 rg-lists per (w,lr) group ----
    __syncthreads();
    float* mval = (float*)smem;
    int*   midx = (int*)(smem + 10240);
    {
        const int g = w*16 + lr;
        #pragma unroll
        for (int s = 0; s < 10; ++s) {
            mval[(g*4 + rg)*10 + s] = vals[s];
            midx[(g*4 + rg)*10 + s] = idxs[s];
        }
    }
    __syncthreads();
    if (t < 128) {   // step 1: merge (pr, pr+2) -> pr for pr in {0,1} of each group
        const int g = t >> 1, pr = t & 1;
        float* va = &mval[(g*4 + pr)*10];     int* ia = &midx[(g*4 + pr)*10];
        const float* vb = &mval[(g*4 + pr + 2)*10]; const int* ib = &midx[(g*4 + pr + 2)*10];
        float ov[10]; int oi[10]; int pa = 0, pb = 0;
        #pragma unroll
        for (int s = 0; s < 10; ++s) {
            const float A = va[pa], Bv = vb[pb];
            const int  Ai = ia[pa], Bi = ib[pb];
            const bool ta = (A > Bv) || (A == Bv && Ai < Bi);
            ov[s] = ta ? A : Bv; oi[s] = ta ? Ai : Bi;
            pa += ta ? 1 : 0; pb += ta ? 0 : 1;
        }
        #pragma unroll
        for (int s = 0; s < 10; ++s) { va[s] = ov[s]; ia[s] = oi[s]; }
    }
    __syncthreads();
    if (t < 64) {    // step 2: final merge per group + write partial
        const int g = t;
        const int i = i0 + g;
        if (i < NPTS) {
            const float* va = &mval[(g*4 + 0)*10]; const int* ia = &midx[(g*4 + 0)*10];
            const float* vb = &mval[(g*4 + 1)*10]; const int* ib = &midx[(g*4 + 1)*10];
            float* ov = &pval[((size_t)(b*NPTS + i)*3 + jh)*10];
            int*   oi = &pidx[((size_t)(b*NPTS + i)*3 + jh)*10];
            int pa = 0, pb = 0;
            #pragma unroll
            for (int s = 0; s < 10; ++s) {
                const float A = va[pa], Bv = vb[pb];
                const int  Ai = ia[pa], Bi = ib[pb];
                const bool ta = (A > Bv) || (A == Bv && Ai < Bi);
                ov[s] = ta ? A : Bv; oi[s] = ta ? Ai : Bi;
                pa += ta ? 1 : 0; pb += ta ? 0 : 1;
            }
        }
    }
}

// ---------------- Kernel M: 3-way heads-merge of j-third partials ----------------
__global__ __launch_bounds__(256) void k_tkmerge(
    const float* __restrict__ pval, const int* __restrict__ pidx,
    int* __restrict__ tk)
{
    const int r = blockIdx.x*256 + threadIdx.x;
    if (r >= NROWS) return;
    const float* v  = &pval[(size_t)r*30];
    const int*   ix = &pidx[(size_t)r*30];
    const int base = (r / NPTS) * NPTS;
    int* op = &tk[(size_t)r*NK];
    int p0 = 0, p1 = 0, p2 = 0;
    #pragma unroll
    for (int s = 0; s < NK; ++s) {
        float bv = -3.4e38f; int bi = 0x7fffffff; int bl = 0;
        {
            const float vv = v[p0];       const int ii = ix[p0];
            if (vv > bv || (vv == bv && ii < bi)) { bv = vv; bi = ii; bl = 0; }
        }
        {
            const float vv = v[10 + p1];  const int ii = ix[10 + p1];
            if (vv > bv || (vv == bv && ii < bi)) { bv = vv; bi = ii; bl = 1; }
        }
        {
            const float vv = v[20 + p2];  const int ii = ix[20 + p2];
            if (vv > bv || (vv == bv && ii < bi)) { bv = vv; bi = ii; bl = 2; }
        }
        p0 += (bl == 0); p1 += (bl == 1); p2 += (bl == 2);
        op[s] = base + bi;
    }
}

// ---------------- Kernel D: fused tail (MFMA phase 2, unchanged) ----------------
#define AST 136
__global__ __launch_bounds__(256, 2) void k_fused(
    const float* __restrict__ x,
    const int* __restrict__ nb, const int* __restrict__ tk,
    const float* __restrict__ T1r, const float* __restrict__ P, const float* __restrict__ Q,
    const float* __restrict__ tW2, const float* __restrict__ tb2,
    const float* __restrict__ sW2, const float* __restrict__ sb2,
    const _Float16* __restrict__ wt3h, const _Float16* __restrict__ ws3h,
    const float* __restrict__ tb3, const float* __restrict__ sb3,
    float* __restrict__ out)
{
    __shared__ __align__(16) _Float16 A16[144*AST];
    __shared__ float Ssm[8][260];
    __shared__ float Zr[8][260];

    const int t  = threadIdx.x;
    const int r0 = blockIdx.x * 8;
    const int bb = r0 / NPTS;
    const int n0 = r0 % NPTS;

    {
        const float4 z4 = make_float4(0.f,0.f,0.f,0.f);
        float4* p4 = (float4*)A16;
        #pragma unroll
        for (int i = 0; i < 10; ++i) {
            const int idx = t + i*256;
            if (idx < 2448) p4[idx] = z4;
        }
    }
    __syncthreads();

    {
        const int o    = t & 127;
        const int half = t >> 7;
        const int g4   = o & ~3;

        const float4 f0 = *(const float4*)&tW2[o*12];
        const float4 f1 = *(const float4*)&tW2[o*12 + 4];
        const float4 f2 = *(const float4*)&tW2[o*12 + 8];
        const float4 wt0 = make_float4(f0.x, f0.w, f1.z, f2.y);
        const float4 wt1 = make_float4(f0.y, f1.x, f1.w, f2.z);
        const float4 wt2 = make_float4(f0.z, f1.y, f2.x, f2.w);
        const float4 wsw = *(const float4*)&sW2[o*4];
        const float tb2o = tb2[o], sb2o = sb2[o];

        #pragma unroll
        for (int ptl = 0; ptl < 4; ++ptl) {
            const int pt = half*4 + ptl;
            const int r  = r0 + pt;
            const int nb0 = nb[r*3+0], nb1 = nb[r*3+1], nb2 = nb[r*3+2];
            int ki[NK];
            #pragma unroll
            for (int k = 0; k < NK; ++k) ki[k] = tk[r*NK + k];
            const float4 h0 = *(const float4*)&T1r[(size_t)nb0*NW + g4];
            const float4 h1 = *(const float4*)&T1r[(size_t)nb1*NW + g4];
            const float4 h2 = *(const float4*)&T1r[(size_t)nb2*NW + g4];
            const float4 qf = *(const float4*)&Q[(size_t)r*NW + g4];
            float4 pf[NK];
            #pragma unroll
            for (int k = 0; k < NK; ++k) pf[k] = *(const float4*)&P[(size_t)ki[k]*NW + g4];

            const float z = tb2o + dot4(wt0,h0) + dot4(wt1,h1) + dot4(wt2,h2);
            A16[(128 + pt)*AST + o] = (_Float16)fmaxf(z, 0.f);
            #pragma unroll
            for (int k = 0; k < NK; ++k) {
                const float4 g1 = relu4(add4(pf[k], qf));
                A16[(pt*16 + k)*AST + o] = (_Float16)fmaxf(dot4(wsw, g1) + sb2o, 0.f);
            }
        }
    }
    __syncthreads();

    const int lane = t & 63, w = t >> 6;
    const int lr = lane & 15, lg = lane >> 4;
    const int n0w = w * 64;

    f32x4 accG[8][4] = {};
    f32x4 accZ[4] = {};

    #pragma unroll
    for (int kt = 0; kt < 4; ++kt) {
        const int ko = kt*32 + lg*8;
        f16x8 bs[4], bt[4];
        #pragma unroll
        for (int nt = 0; nt < 4; ++nt) {
            const int n = n0w + nt*16 + lr;
            bs[nt] = *(const f16x8*)&ws3h[n*NW + ko];
            bt[nt] = *(const f16x8*)&wt3h[n*NW + ko];
        }
        #pragma unroll
        for (int mt = 0; mt < 8; ++mt) {
            const f16x8 a = *(const f16x8*)&A16[(mt*16 + lr)*AST + ko];
            #pragma unroll
            for (int nt = 0; nt < 4; ++nt)
                accG[mt][nt] = __builtin_amdgcn_mfma_f32_16x16x32_f16(a, bs[nt], accG[mt][nt], 0,0,0);
        }
        const f16x8 az = *(const f16x8*)&A16[(128 + lr)*AST + ko];
        #pragma unroll
        for (int nt = 0; nt < 4; ++nt)
            accZ[nt] = __builtin_amdgcn_mfma_f32_16x16x32_f16(az, bt[nt], accZ[nt], 0,0,0);
    }

    const int rg = lg;
    #pragma unroll
    for (int mt = 0; mt < 8; ++mt) {
        #pragma unroll
        for (int nt = 0; nt < 4; ++nt) {
            float v;
            if (rg < 2)       v = fmaxf(fmaxf(accG[mt][nt][0], accG[mt][nt][1]),
                                        fmaxf(accG[mt][nt][2], accG[mt][nt][3]));
            else if (rg == 2) v = fmaxf(accG[mt][nt][0], accG[mt][nt][1]);
            else              v = -3.0e38f;
            v = fmaxf(v, __shfl_xor(v, 16));
            v = fmaxf(v, __shfl_xor(v, 32));
            if (lane < 16) Ssm[mt][n0w + nt*16 + lane] = v;
        }
    }
    #pragma unroll
    for (int nt = 0; nt < 4; ++nt) {
        #pragma unroll
        for (int q = 0; q < 4; ++q) {
            if (rg < 2) Zr[rg*4 + q][n0w + nt*16 + lr] = accZ[nt][q];
        }
    }
    __syncthreads();

    {
        const int c = t;
        const float tb = tb3[c], sb = sb3[c];
        const size_t go = ((size_t)bb*NC + c)*NPTS + n0;
        const float4 xv0 = *(const float4*)&x[go];
        const float4 xv1 = *(const float4*)&x[go + 4];
        const float xr[8] = {xv0.x,xv0.y,xv0.z,xv0.w, xv1.x,xv1.y,xv1.z,xv1.w};
        float ov[8];
        #pragma unroll
        for (int p = 0; p < 8; ++p)
            ov[p] = fmaxf(Zr[p][c] + tb + Ssm[p][c] + sb + xr[p], 0.f);
        *(float4*)&out[go]     = make_float4(ov[0],ov[1],ov[2],ov[3]);
        *(float4*)&out[go + 4] = make_float4(ov[4],ov[5],ov[6],ov[7]);
    }
}

extern "C" void kernel_launch(void* const* d_in, const int* in_sizes, int n_in,
                              void* d_out, int out_size, void* d_ws, size_t ws_size,
                              hipStream_t stream) {
    (void)in_sizes; (void)n_in; (void)out_size; (void)ws_size;
    const float* x   = (const float*)d_in[0];
    const int*   nb  = (const int*)d_in[2];
    const float* tW1 = (const float*)d_in[3];
    const float* tb1 = (const float*)d_in[4];
    const float* tW2 = (const float*)d_in[5];
    const float* tb2 = (const float*)d_in[6];
    const float* tW3 = (const float*)d_in[7];
    const float* tb3 = (const float*)d_in[8];
    const float* sW1 = (const float*)d_in[9];
    const float* sb1 = (const float*)d_in[10];
    const float* sW2 = (const float*)d_in[11];
    const float* sb2 = (const float*)d_in[12];
    const float* sW3 = (const float*)d_in[13];
    const float* sb3 = (const float*)d_in[14];
    float* out = (float*)d_out;

    float* ws  = (float*)d_ws;
    float* T1r  = ws;                       // 2,048,000 f32
    float* P    = ws + 2048000;             // 2,048,000 f32
    float* Q    = ws + 4096000;             // 2,048,000 f32
    float* xxp  = ws + 6144000;             // 16,000 f32
    int*   tk   = (int*)(ws + 6160000);     // 160,000 int
    float* pval = ws + 6320000;             // 480,000 f32
    int*   pidx = (int*)(ws + 6800000);     // 480,000 int
    _Float16* xb   = (_Float16*)(ws + 7280000);   // 8,388,608 f16
    _Float16* wt3h = xb + (size_t)NBATCH * 16 * PL2;
    _Float16* ws3h = wt3h + NC * NW;

    k_prep<<<NBATCH * 32, 256, 0, stream>>>(x, xb, xxp);
    k_wprep<<<32, 256, 0, stream>>>(tW3, wt3h, NC * NW);
    k_wprep<<<32, 256, 0, stream>>>(sW3, ws3h, NC * NW);
    k_rowgemm<<<dim3(NROWS / 32, 3), 256, 0, stream>>>(x, tW1, tb1, sW1, sb1, T1r, P, Q);
    k_topk<<<768, 256, 0, stream>>>(xb, xxp, pval, pidx);
    k_tkmerge<<<(NROWS + 255) / 256, 256, 0, stream>>>(pval, pidx, tk);
    k_fused<<<NROWS / 8, 256, 0, stream>>>(x, nb, tk, T1r, P, Q,
                                           tW2, tb2, sW2, sb2, wt3h, ws3h, tb3, sb3, out);
}